// Round 1
// baseline (1912.552 us; speedup 1.0000x reference)
//
#include <hip/hip_runtime.h>
#include <hip/hip_bf16.h>

#define N1 131072
#define E1 2097152
#define N2 2368
#define E2 37888
#define NROIS 148
#define BSZ 16
#define HID 64
#define INCH 128
#define NSEG (BSZ*NROIS)      /* 2368 */
#define SDIM (NROIS*HID)      /* 9472 */
#define CLS 1000
#define OCH 2
#define KCH 592               /* 9472/16 */

__global__ void k_init_deg(float* __restrict__ deg, int n) {
    int i = blockIdx.x * blockDim.x + threadIdx.x;
    if (i < n) deg[i] = 1.0f;   // self-loop weight 1
}

__global__ void k_deg(float* __restrict__ deg, const int* __restrict__ dst,
                      const float* __restrict__ ew, int E) {
    int e = blockIdx.x * blockDim.x + threadIdx.x;
    if (e < E) unsafeAtomicAdd(&deg[dst[e]], ew[e]);
}

__global__ void k_rsqrt(float* __restrict__ d, int n) {
    int i = blockIdx.x * blockDim.x + threadIdx.x;
    if (i < n) d[i] = rsqrtf(d[i]);
}

__global__ void k_norm(float* __restrict__ nrm, const int* __restrict__ src,
                       const int* __restrict__ dst, const float* __restrict__ ew,
                       const float* __restrict__ dinv, int E) {
    int e = blockIdx.x * blockDim.x + threadIdx.x;
    if (e < E) nrm[e] = dinv[src[e]] * ew[e] * dinv[dst[e]];
}

// out[n][HID] = x[n][K] @ W[K][HID].  W staged in LDS; x row broadcast float4.
template <int K>
__global__ __launch_bounds__(256) void k_gemm(float* __restrict__ out,
                                              const float* __restrict__ x,
                                              const float* __restrict__ W, int n) {
    __shared__ float Wl[K * HID];
    int tid = threadIdx.x;
    {
        const float4* W4 = (const float4*)W;
        float4* Wl4 = (float4*)Wl;
        for (int i = tid; i < K * HID / 4; i += 256) Wl4[i] = W4[i];
    }
    __syncthreads();
    int col = tid & 63, rl = tid >> 6;
    int row0 = blockIdx.x * 16;
    for (int r = rl; r < 16; r += 4) {
        int row = row0 + r;
        if (row < n) {
            const float4* xr = (const float4*)(x + (size_t)row * K);
            float acc = 0.f;
#pragma unroll
            for (int k4 = 0; k4 < K / 4; k4++) {
                float4 xv = xr[k4];
                acc += xv.x * Wl[(k4 * 4 + 0) * HID + col];
                acc += xv.y * Wl[(k4 * 4 + 1) * HID + col];
                acc += xv.z * Wl[(k4 * 4 + 2) * HID + col];
                acc += xv.w * Wl[(k4 * 4 + 3) * HID + col];
            }
            out[(size_t)row * HID + col] = acc;
        }
    }
}

// acc[dst] += h[src] * norm, one 64-lane slot per edge
__global__ __launch_bounds__(256) void k_scatter(float* __restrict__ acc,
                                                 const float* __restrict__ h,
                                                 const int* __restrict__ src,
                                                 const int* __restrict__ dst,
                                                 const float* __restrict__ nrm, int E) {
    int e = blockIdx.x * 4 + (threadIdx.x >> 6);
    if (e >= E) return;
    int c = threadIdx.x & 63;
    int s = src[e], d = dst[e];
    float nv = nrm[e];
    unsafeAtomicAdd(&acc[(size_t)d * HID + c], h[(size_t)s * HID + c] * nv);
}

// acc = relu(acc + hlin*dinv^2 + b), in place
__global__ void k_fin(float* __restrict__ acc, const float* __restrict__ hlin,
                      const float* __restrict__ dinv, const float* __restrict__ b, int n) {
    int i = blockIdx.x * blockDim.x + threadIdx.x;
    if (i >= n * HID) return;
    int node = i >> 6, c = i & 63;
    float di = dinv[node];
    float v = acc[i] + hlin[i] * di * di + b[c];
    acc[i] = v > 0.f ? v : 0.f;
}

__global__ __launch_bounds__(256) void k_pool(float* __restrict__ sums, float* __restrict__ cnt,
                                              const float* __restrict__ h,
                                              const int* __restrict__ batch,
                                              const int* __restrict__ label, int n) {
    int node = blockIdx.x * 4 + (threadIdx.x >> 6);
    if (node >= n) return;
    int c = threadIdx.x & 63;
    int seg = batch[node] * NROIS + label[node];
    unsafeAtomicAdd(&sums[(size_t)seg * HID + c], h[(size_t)node * HID + c]);
    if (c == 0) unsafeAtomicAdd(&cnt[seg], 1.0f);
}

__global__ void k_pool_fin(float* __restrict__ emb1, float* __restrict__ emb2,
                           float* __restrict__ esum, const float* __restrict__ cnt1,
                           const float* __restrict__ cnt2) {
    int i = blockIdx.x * blockDim.x + threadIdx.x;
    if (i >= NSEG * HID) return;
    int seg = i >> 6;
    float m1 = emb1[i] / fmaxf(cnt1[seg], 1.0f);
    float m2 = emb2[i] / fmaxf(cnt2[seg], 1.0f);
    emb1[i] = m1;
    emb2[i] = m2;
    esum[i] = m1 + m2;
}

// hcls[16][1000] += s[16][9472] @ Wm1[9472][1000] over k-chunk blockIdx.y
__global__ __launch_bounds__(256) void k_cls(float* __restrict__ hcls,
                                             const float* __restrict__ s,
                                             const float* __restrict__ Wm1) {
    int col = blockIdx.x * 64 + (threadIdx.x & 63);
    int ty = threadIdx.x >> 6;  // 0..3
    int k0 = blockIdx.y * KCH, k1 = k0 + KCH;
    if (col >= CLS) return;
    float a0 = 0.f, a1 = 0.f, a2 = 0.f, a3 = 0.f;
    for (int k = k0; k < k1; k++) {
        float w = Wm1[(size_t)k * CLS + col];
        a0 += s[(ty + 0) * SDIM + k] * w;
        a1 += s[(ty + 4) * SDIM + k] * w;
        a2 += s[(ty + 8) * SDIM + k] * w;
        a3 += s[(ty + 12) * SDIM + k] * w;
    }
    unsafeAtomicAdd(&hcls[(ty + 0) * CLS + col], a0);
    unsafeAtomicAdd(&hcls[(ty + 4) * CLS + col], a1);
    unsafeAtomicAdd(&hcls[(ty + 8) * CLS + col], a2);
    unsafeAtomicAdd(&hcls[(ty + 12) * CLS + col], a3);
}

__global__ void k_bn(float* __restrict__ hact, const float* __restrict__ hcls,
                     const float* __restrict__ bm1, const float* __restrict__ gamma,
                     const float* __restrict__ beta, const float* __restrict__ mean,
                     const float* __restrict__ var) {
    int i = blockIdx.x * blockDim.x + threadIdx.x;
    if (i >= BSZ * CLS) return;
    int j = i % CLS;
    float t = hcls[i] + bm1[j];
    t = gamma[j] * (t - mean[j]) * rsqrtf(var[j] + 1e-5f) + beta[j];
    hact[i] = t > 0.f ? t : 0.01f * t;
}

__global__ void k_out(float* __restrict__ outp, const float* __restrict__ hact,
                      const float* __restrict__ Wm2, const float* __restrict__ bm2) {
    int tid = threadIdx.x;           // one block of 256
    int oi = tid >> 3, part = tid & 7;  // 32 outputs x 8 partials
    int b = oi >> 1, o = oi & 1;
    float acc = (part == 0) ? bm2[o] : 0.f;
    for (int k = part; k < CLS; k += 8) acc += hact[b * CLS + k] * Wm2[k * OCH + o];
    unsafeAtomicAdd(&outp[b * OCH + o], acc);
}

extern "C" void kernel_launch(void* const* d_in, const int* in_sizes, int n_in,
                              void* d_out, int out_size, void* d_ws, size_t ws_size,
                              hipStream_t stream) {
    const float* x1  = (const float*)d_in[0];
    const int*   nl  = (const int*)d_in[1];
    const int*   ei1 = (const int*)d_in[2];
    const float* ew1 = (const float*)d_in[3];
    const int*   ba1 = (const int*)d_in[4];
    const float* x2  = (const float*)d_in[5];
    const int*   rl  = (const int*)d_in[6];
    const int*   ei2 = (const int*)d_in[7];
    const float* ew2 = (const float*)d_in[8];
    const int*   ba2 = (const int*)d_in[9];
    const float* W1a = (const float*)d_in[10];
    const float* b1a = (const float*)d_in[11];
    const float* W1b = (const float*)d_in[12];
    const float* b1b = (const float*)d_in[13];
    const float* W2a = (const float*)d_in[14];
    const float* b2a = (const float*)d_in[15];
    const float* W2b = (const float*)d_in[16];
    const float* b2b = (const float*)d_in[17];
    const float* Wm1 = (const float*)d_in[18];
    const float* bm1 = (const float*)d_in[19];
    const float* gam = (const float*)d_in[20];
    const float* bet = (const float*)d_in[21];
    const float* bmn = (const float*)d_in[22];
    const float* bvr = (const float*)d_in[23];
    const float* Wm2 = (const float*)d_in[24];
    const float* bm2 = (const float*)d_in[25];

    float* out  = (float*)d_out;
    float* emb1 = out + 32;               // embedding        (16 x 9472)
    float* emb2 = emb1 + NSEG * HID;      // embedding_roi
    float* esum = emb2 + NSEG * HID;      // embedding + embedding_roi

    float* ws    = (float*)d_ws;
    float* dinv1 = ws;                     // N1
    float* norm1 = dinv1 + N1;             // E1
    float* A1    = norm1 + E1;             // N1*HID
    float* B1    = A1 + (size_t)N1 * HID;  // N1*HID
    float* dinv2 = B1 + (size_t)N1 * HID;  // N2
    float* norm2 = dinv2 + N2;             // E2
    float* A2    = norm2 + E2;             // N2*HID
    float* B2    = A2 + (size_t)N2 * HID;  // N2*HID
    float* cnt1  = B2 + (size_t)N2 * HID;  // NSEG
    float* cnt2  = cnt1 + NSEG;            // NSEG
    float* hcls  = cnt2 + NSEG;            // 16*1000
    float* hact  = hcls + BSZ * CLS;       // 16*1000

    const int* src1 = ei1;
    const int* dst1 = ei1 + E1;
    const int* src2 = ei2;
    const int* dst2 = ei2 + E2;

    hipMemsetAsync(d_out, 0, (size_t)out_size * sizeof(float), stream);
    hipMemsetAsync(cnt1, 0, (size_t)(2 * NSEG + BSZ * CLS) * sizeof(float), stream);

    // ---------------- graph 2 (ROI graph, small) ----------------
    k_init_deg<<<(N2 + 255) / 256, 256, 0, stream>>>(dinv2, N2);
    k_deg<<<(E2 + 255) / 256, 256, 0, stream>>>(dinv2, dst2, ew2, E2);
    k_rsqrt<<<(N2 + 255) / 256, 256, 0, stream>>>(dinv2, N2);
    k_norm<<<(E2 + 255) / 256, 256, 0, stream>>>(norm2, src2, dst2, ew2, dinv2, E2);

    k_gemm<INCH><<<(N2 + 15) / 16, 256, 0, stream>>>(A2, x2, W2a, N2);
    hipMemsetAsync(B2, 0, (size_t)N2 * HID * sizeof(float), stream);
    k_scatter<<<(E2 + 3) / 4, 256, 0, stream>>>(B2, A2, src2, dst2, norm2, E2);
    k_fin<<<(N2 * HID + 255) / 256, 256, 0, stream>>>(B2, A2, dinv2, b2a, N2);

    k_gemm<HID><<<(N2 + 15) / 16, 256, 0, stream>>>(A2, B2, W2b, N2);
    hipMemsetAsync(B2, 0, (size_t)N2 * HID * sizeof(float), stream);
    k_scatter<<<(E2 + 3) / 4, 256, 0, stream>>>(B2, A2, src2, dst2, norm2, E2);
    k_fin<<<(N2 * HID + 255) / 256, 256, 0, stream>>>(B2, A2, dinv2, b2b, N2);

    k_pool<<<(N2 + 3) / 4, 256, 0, stream>>>(emb2, cnt2, B2, ba2, rl, N2);

    // ---------------- graph 1 (fine-grained, large) ----------------
    k_init_deg<<<(N1 + 255) / 256, 256, 0, stream>>>(dinv1, N1);
    k_deg<<<(E1 + 255) / 256, 256, 0, stream>>>(dinv1, dst1, ew1, E1);
    k_rsqrt<<<(N1 + 255) / 256, 256, 0, stream>>>(dinv1, N1);
    k_norm<<<(E1 + 255) / 256, 256, 0, stream>>>(norm1, src1, dst1, ew1, dinv1, E1);

    k_gemm<INCH><<<(N1 + 15) / 16, 256, 0, stream>>>(A1, x1, W1a, N1);
    hipMemsetAsync(B1, 0, (size_t)N1 * HID * sizeof(float), stream);
    k_scatter<<<(E1 + 3) / 4, 256, 0, stream>>>(B1, A1, src1, dst1, norm1, E1);
    k_fin<<<(N1 * HID + 255) / 256, 256, 0, stream>>>(B1, A1, dinv1, b1a, N1);

    k_gemm<HID><<<(N1 + 15) / 16, 256, 0, stream>>>(A1, B1, W1b, N1);
    hipMemsetAsync(B1, 0, (size_t)N1 * HID * sizeof(float), stream);
    k_scatter<<<(E1 + 3) / 4, 256, 0, stream>>>(B1, A1, src1, dst1, norm1, E1);
    k_fin<<<(N1 * HID + 255) / 256, 256, 0, stream>>>(B1, A1, dinv1, b1b, N1);

    k_pool<<<(N1 + 3) / 4, 256, 0, stream>>>(emb1, cnt1, B1, ba1, nl, N1);

    // ---------------- classifier ----------------
    k_pool_fin<<<(NSEG * HID + 255) / 256, 256, 0, stream>>>(emb1, emb2, esum, cnt1, cnt2);
    k_cls<<<dim3(16, 16), 256, 0, stream>>>(hcls, esum, Wm1);
    k_bn<<<(BSZ * CLS + 255) / 256, 256, 0, stream>>>(hact, hcls, bm1, gam, bet, bmn, bvr);
    k_out<<<1, 256, 0, stream>>>(out, hact, Wm2, bm2);
}

// Round 3
// 1346.143 us; speedup vs baseline: 1.4208x; 1.4208x over previous
//
#include <hip/hip_runtime.h>
#include <hip/hip_bf16.h>

#define N1 131072
#define E1 2097152
#define N2 2368
#define E2 37888
#define NROIS 148
#define BSZ 16
#define HID 64
#define INCH 128
#define NSEG (BSZ*NROIS)      /* 2368 */
#define SDIM (NROIS*HID)      /* 9472 */
#define CLS 1000
#define OCH 2
#define KCH 592               /* 9472/16 */

// ---------------- CSR build: histogram / scan / fill ----------------

__global__ void k_hist_dst(int* __restrict__ cnt, const int* __restrict__ dst, int E) {
    int e = blockIdx.x * 256 + threadIdx.x;
    if (e < E) atomicAdd(&cnt[dst[e]], 1);
}

__global__ void k_hist_seg(int* __restrict__ cnt, const int* __restrict__ batch,
                           const int* __restrict__ label, int n) {
    int i = blockIdx.x * 256 + threadIdx.x;
    if (i < n) atomicAdd(&cnt[batch[i] * NROIS + label[i]], 1);
}

// exclusive scan, stage 1: each block scans 1024 elements
__global__ void k_scan1(const int* __restrict__ in, int* __restrict__ out,
                        int* __restrict__ part, int n) {
    __shared__ int sh[256];
    int t = threadIdx.x;
    int i0 = blockIdx.x * 1024 + t * 4;
    int v0 = (i0     < n) ? in[i0]     : 0;
    int v1 = (i0 + 1 < n) ? in[i0 + 1] : 0;
    int v2 = (i0 + 2 < n) ? in[i0 + 2] : 0;
    int v3 = (i0 + 3 < n) ? in[i0 + 3] : 0;
    int tot = v0 + v1 + v2 + v3;
    sh[t] = tot; __syncthreads();
    for (int off = 1; off < 256; off <<= 1) {
        int x = 0; if (t >= off) x = sh[t - off];
        __syncthreads();
        if (t >= off) sh[t] += x;
        __syncthreads();
    }
    int excl = sh[t] - tot;
    if (t == 255) part[blockIdx.x] = sh[255];
    if (i0     < n) out[i0]     = excl;
    if (i0 + 1 < n) out[i0 + 1] = excl + v0;
    if (i0 + 2 < n) out[i0 + 2] = excl + v0 + v1;
    if (i0 + 3 < n) out[i0 + 3] = excl + v0 + v1 + v2;
}

// stage 2: single block, exclusive scan of block partials (cnt <= 256)
__global__ void k_scan2(int* __restrict__ part, int cnt) {
    __shared__ int sh[256];
    int t = threadIdx.x;
    int v = (t < cnt) ? part[t] : 0;
    sh[t] = v; __syncthreads();
    for (int off = 1; off < 256; off <<= 1) {
        int x = 0; if (t >= off) x = sh[t - off];
        __syncthreads();
        if (t >= off) sh[t] += x;
        __syncthreads();
    }
    if (t < cnt) part[t] = sh[t] - v;
}

// stage 3: add block offsets, write sentinel rowptr[n] = total
__global__ void k_scan3(int* __restrict__ out, const int* __restrict__ part, int n, int total) {
    int i = blockIdx.x * 256 + threadIdx.x;
    if (i < n) out[i] += part[i >> 10];
    if (i == 0) out[n] = total;
}

__global__ void k_fill_edges(int* __restrict__ srcp, float* __restrict__ ewp,
                             int* __restrict__ off, const int* __restrict__ src,
                             const int* __restrict__ dst, const float* __restrict__ ew, int E) {
    int e = blockIdx.x * 256 + threadIdx.x;
    if (e >= E) return;
    int pos = atomicAdd(&off[dst[e]], 1);
    srcp[pos] = src[e];
    ewp[pos] = ew[e];
}

__global__ void k_fill_seg(int* __restrict__ nodeid, int* __restrict__ off,
                           const int* __restrict__ batch, const int* __restrict__ label, int n) {
    int i = blockIdx.x * 256 + threadIdx.x;
    if (i >= n) return;
    int pos = atomicAdd(&off[batch[i] * NROIS + label[i]], 1);
    nodeid[pos] = i;
}

// dinv[d] = rsqrt(1 + sum of in-edge weights)
__global__ void k_deg_dinv(float* __restrict__ dinv, const int* __restrict__ row,
                           const float* __restrict__ ewp, int n) {
    int d = blockIdx.x * 256 + threadIdx.x;
    if (d >= n) return;
    int a = row[d], b = row[d + 1];
    float s = 1.0f;
    for (int i = a; i < b; i++) s += ewp[i];
    dinv[d] = rsqrtf(s);
}

// normp[i] = dinv[src]*ew*dinv[dst], in place over ewp
__global__ void k_scale(float* __restrict__ normp, const int* __restrict__ srcp,
                        const int* __restrict__ row, const float* __restrict__ dinv, int n) {
    int d = blockIdx.x * 256 + threadIdx.x;
    if (d >= n) return;
    int a = row[d], b = row[d + 1];
    float dd = dinv[d];
    for (int i = a; i < b; i++) normp[i] = dinv[srcp[i]] * normp[i] * dd;
}

// ---------------- dense ops ----------------

// out[n][HID] = x[n][K] @ W[K][HID].  W staged in LDS; x row broadcast float4.
template <int K>
__global__ __launch_bounds__(256) void k_gemm(float* __restrict__ out,
                                              const float* __restrict__ x,
                                              const float* __restrict__ W, int n) {
    __shared__ float Wl[K * HID];
    int tid = threadIdx.x;
    {
        const float4* W4 = (const float4*)W;
        float4* Wl4 = (float4*)Wl;
        for (int i = tid; i < K * HID / 4; i += 256) Wl4[i] = W4[i];
    }
    __syncthreads();
    int col = tid & 63, rl = tid >> 6;
    int row0 = blockIdx.x * 16;
    for (int r = rl; r < 16; r += 4) {
        int row = row0 + r;
        if (row < n) {
            const float4* xr = (const float4*)(x + (size_t)row * K);
            float acc = 0.f;
#pragma unroll
            for (int k4 = 0; k4 < K / 4; k4++) {
                float4 xv = xr[k4];
                acc += xv.x * Wl[(k4 * 4 + 0) * HID + col];
                acc += xv.y * Wl[(k4 * 4 + 1) * HID + col];
                acc += xv.z * Wl[(k4 * 4 + 2) * HID + col];
                acc += xv.w * Wl[(k4 * 4 + 3) * HID + col];
            }
            out[(size_t)row * HID + col] = acc;
        }
    }
}

// fused GCN aggregate: wave per dst node, lane = feature column.
// out[d] = relu( sum_e h[src_e]*norm_e + h[d]*dinv[d]^2 + bias )
__global__ __launch_bounds__(256) void k_conv(float* __restrict__ out, const float* __restrict__ h,
                                              const int* __restrict__ srcp,
                                              const float* __restrict__ normp,
                                              const int* __restrict__ row,
                                              const float* __restrict__ dinv,
                                              const float* __restrict__ bias, int n) {
    int d = blockIdx.x * 4 + (threadIdx.x >> 6);
    if (d >= n) return;
    int lane = threadIdx.x & 63;
    int a = row[d], b = row[d + 1];
    float acc = 0.f;
    for (int base = a; base < b; base += 64) {
        int m = b - base; if (m > 64) m = 64;
        int sv = 0; float nv = 0.f;
        if (base + lane < b) { sv = srcp[base + lane]; nv = normp[base + lane]; }
        for (int j = 0; j < m; j++) {
            int s = __shfl(sv, j);
            float w = __shfl(nv, j);
            acc += h[(size_t)s * HID + lane] * w;
        }
    }
    float di = dinv[d];
    float v = acc + h[(size_t)d * HID + lane] * di * di + bias[lane];
    out[(size_t)d * HID + lane] = v > 0.f ? v : 0.f;
}

// segment-mean pool: wave per segment; counts from rowptr diff.
__global__ __launch_bounds__(256) void k_pool(float* __restrict__ emb, float* __restrict__ esum,
                                              const float* __restrict__ embo,
                                              const float* __restrict__ h,
                                              const int* __restrict__ nodeid,
                                              const int* __restrict__ segrow) {
    int s = blockIdx.x * 4 + (threadIdx.x >> 6);
    if (s >= NSEG) return;
    int lane = threadIdx.x & 63;
    int a = segrow[s], b = segrow[s + 1];
    float acc = 0.f;
    for (int base = a; base < b; base += 64) {
        int m = b - base; if (m > 64) m = 64;
        int nid = 0;
        if (base + lane < b) nid = nodeid[base + lane];
        for (int j = 0; j < m; j++) {
            int nn = __shfl(nid, j);
            acc += h[(size_t)nn * HID + lane];
        }
    }
    float mean = acc / fmaxf((float)(b - a), 1.0f);
    emb[(size_t)s * HID + lane] = mean;
    if (esum) esum[(size_t)s * HID + lane] = mean + embo[(size_t)s * HID + lane];
}

// ---------------- classifier ----------------

__global__ __launch_bounds__(256) void k_cls(float* __restrict__ hcls,
                                             const float* __restrict__ s,
                                             const float* __restrict__ Wm1) {
    int col = blockIdx.x * 64 + (threadIdx.x & 63);
    int ty = threadIdx.x >> 6;  // 0..3
    int k0 = blockIdx.y * KCH, k1 = k0 + KCH;
    if (col >= CLS) return;
    float a0 = 0.f, a1 = 0.f, a2 = 0.f, a3 = 0.f;
    for (int k = k0; k < k1; k++) {
        float w = Wm1[(size_t)k * CLS + col];
        a0 += s[(ty + 0) * SDIM + k] * w;
        a1 += s[(ty + 4) * SDIM + k] * w;
        a2 += s[(ty + 8) * SDIM + k] * w;
        a3 += s[(ty + 12) * SDIM + k] * w;
    }
    unsafeAtomicAdd(&hcls[(ty + 0) * CLS + col], a0);
    unsafeAtomicAdd(&hcls[(ty + 4) * CLS + col], a1);
    unsafeAtomicAdd(&hcls[(ty + 8) * CLS + col], a2);
    unsafeAtomicAdd(&hcls[(ty + 12) * CLS + col], a3);
}

__global__ void k_bn(float* __restrict__ hact, const float* __restrict__ hcls,
                     const float* __restrict__ bm1, const float* __restrict__ gamma,
                     const float* __restrict__ beta, const float* __restrict__ mean,
                     const float* __restrict__ var) {
    int i = blockIdx.x * blockDim.x + threadIdx.x;
    if (i >= BSZ * CLS) return;
    int j = i % CLS;
    float t = hcls[i] + bm1[j];
    t = gamma[j] * (t - mean[j]) * rsqrtf(var[j] + 1e-5f) + beta[j];
    hact[i] = t > 0.f ? t : 0.01f * t;
}

__global__ void k_out(float* __restrict__ outp, const float* __restrict__ hact,
                      const float* __restrict__ Wm2, const float* __restrict__ bm2) {
    int tid = threadIdx.x;              // one block of 256
    int oi = tid >> 3, part = tid & 7;  // 32 outputs x 8 partials
    int b = oi >> 1, o = oi & 1;
    float acc = (part == 0) ? bm2[o] : 0.f;
    for (int k = part; k < CLS; k += 8) acc += hact[b * CLS + k] * Wm2[k * OCH + o];
    unsafeAtomicAdd(&outp[b * OCH + o], acc);
}

extern "C" void kernel_launch(void* const* d_in, const int* in_sizes, int n_in,
                              void* d_out, int out_size, void* d_ws, size_t ws_size,
                              hipStream_t stream) {
    const float* x1  = (const float*)d_in[0];
    const int*   nl  = (const int*)d_in[1];
    const int*   ei1 = (const int*)d_in[2];
    const float* ew1 = (const float*)d_in[3];
    const int*   ba1 = (const int*)d_in[4];
    const float* x2  = (const float*)d_in[5];
    const int*   rl  = (const int*)d_in[6];
    const int*   ei2 = (const int*)d_in[7];
    const float* ew2 = (const float*)d_in[8];
    const int*   ba2 = (const int*)d_in[9];
    const float* W1a = (const float*)d_in[10];
    const float* b1a = (const float*)d_in[11];
    const float* W1b = (const float*)d_in[12];
    const float* b1b = (const float*)d_in[13];
    const float* W2a = (const float*)d_in[14];
    const float* b2a = (const float*)d_in[15];
    const float* W2b = (const float*)d_in[16];
    const float* b2b = (const float*)d_in[17];
    const float* Wm1 = (const float*)d_in[18];
    const float* bm1 = (const float*)d_in[19];
    const float* gam = (const float*)d_in[20];
    const float* bet = (const float*)d_in[21];
    const float* bmn = (const float*)d_in[22];
    const float* bvr = (const float*)d_in[23];
    const float* Wm2 = (const float*)d_in[24];
    const float* bm2 = (const float*)d_in[25];

    float* out  = (float*)d_out;
    float* emb1 = out + 32;               // embedding        (16 x 9472)
    float* emb2 = emb1 + NSEG * HID;      // embedding_roi
    float* esum = emb2 + NSEG * HID;      // embedding + embedding_roi

    // ---- workspace carve ----
    char* p = (char*)d_ws;
    auto carve = [&](size_t nbytes) { char* q = p; p += (nbytes + 255) & ~(size_t)255; return (void*)q; };
    int*   row1    = (int*)  carve((N1 + 1) * 4);
    int*   off1    = (int*)  carve(N1 * 4);
    int*   srcp1   = (int*)  carve((size_t)E1 * 4);
    float* ewp1    = (float*)carve((size_t)E1 * 4);   // becomes normp
    float* dinv1   = (float*)carve(N1 * 4);
    float* A1      = (float*)carve((size_t)N1 * HID * 4);
    float* B1      = (float*)carve((size_t)N1 * HID * 4);
    int*   nodeid1 = (int*)  carve(N1 * 4);
    int*   segrow1 = (int*)  carve((NSEG + 1) * 4);
    int*   segoff1 = (int*)  carve(NSEG * 4);
    int*   row2    = (int*)  carve((N2 + 1) * 4);
    int*   off2    = (int*)  carve(N2 * 4);
    int*   srcp2   = (int*)  carve((size_t)E2 * 4);
    float* ewp2    = (float*)carve((size_t)E2 * 4);
    float* dinv2   = (float*)carve(N2 * 4);
    float* A2      = (float*)carve((size_t)N2 * HID * 4);
    float* B2      = (float*)carve((size_t)N2 * HID * 4);
    int*   nodeid2 = (int*)  carve(N2 * 4);
    int*   segrow2 = (int*)  carve((NSEG + 1) * 4);
    int*   segoff2 = (int*)  carve(NSEG * 4);
    int*   part    = (int*)  carve(256 * 4);
    float* hcls    = (float*)carve(BSZ * CLS * 4);
    float* hact    = (float*)carve(BSZ * CLS * 4);

    const int* src1 = ei1;
    const int* dst1 = ei1 + E1;
    const int* src2 = ei2;
    const int* dst2 = ei2 + E2;

    hipMemsetAsync(d_out, 0, (size_t)out_size * sizeof(float), stream);
    hipMemsetAsync(hcls, 0, BSZ * CLS * sizeof(float), stream);

    // ---------------- graph 2 (ROI graph, small) ----------------
    hipMemsetAsync(off2, 0, N2 * 4, stream);
    k_hist_dst<<<(E2 + 255) / 256, 256, 0, stream>>>(off2, dst2, E2);
    k_scan1<<<(N2 + 1023) / 1024, 256, 0, stream>>>(off2, row2, part, N2);
    k_scan2<<<1, 256, 0, stream>>>(part, (N2 + 1023) / 1024);
    k_scan3<<<(N2 + 255) / 256, 256, 0, stream>>>(row2, part, N2, E2);
    hipMemcpyAsync(off2, row2, N2 * 4, hipMemcpyDeviceToDevice, stream);
    k_fill_edges<<<(E2 + 255) / 256, 256, 0, stream>>>(srcp2, ewp2, off2, src2, dst2, ew2, E2);
    k_deg_dinv<<<(N2 + 255) / 256, 256, 0, stream>>>(dinv2, row2, ewp2, N2);
    k_scale<<<(N2 + 255) / 256, 256, 0, stream>>>(ewp2, srcp2, row2, dinv2, N2);

    k_gemm<INCH><<<(N2 + 15) / 16, 256, 0, stream>>>(A2, x2, W2a, N2);
    k_conv<<<(N2 + 3) / 4, 256, 0, stream>>>(B2, A2, srcp2, ewp2, row2, dinv2, b2a, N2);
    k_gemm<HID><<<(N2 + 15) / 16, 256, 0, stream>>>(A2, B2, W2b, N2);
    k_conv<<<(N2 + 3) / 4, 256, 0, stream>>>(B2, A2, srcp2, ewp2, row2, dinv2, b2b, N2);
    // graph-2 final features now in B2

    hipMemsetAsync(segoff2, 0, NSEG * 4, stream);
    k_hist_seg<<<(N2 + 255) / 256, 256, 0, stream>>>(segoff2, ba2, rl, N2);
    k_scan1<<<(NSEG + 1023) / 1024, 256, 0, stream>>>(segoff2, segrow2, part, NSEG);
    k_scan2<<<1, 256, 0, stream>>>(part, (NSEG + 1023) / 1024);
    k_scan3<<<(NSEG + 255) / 256, 256, 0, stream>>>(segrow2, part, NSEG, N2);
    hipMemcpyAsync(segoff2, segrow2, NSEG * 4, hipMemcpyDeviceToDevice, stream);
    k_fill_seg<<<(N2 + 255) / 256, 256, 0, stream>>>(nodeid2, segoff2, ba2, rl, N2);
    k_pool<<<(NSEG + 3) / 4, 256, 0, stream>>>(emb2, (float*)nullptr, (const float*)nullptr,
                                               B2, nodeid2, segrow2);

    // ---------------- graph 1 (fine-grained, large) ----------------
    hipMemsetAsync(off1, 0, N1 * 4, stream);
    k_hist_dst<<<(E1 + 255) / 256, 256, 0, stream>>>(off1, dst1, E1);
    k_scan1<<<(N1 + 1023) / 1024, 256, 0, stream>>>(off1, row1, part, N1);
    k_scan2<<<1, 256, 0, stream>>>(part, (N1 + 1023) / 1024);
    k_scan3<<<(N1 + 255) / 256, 256, 0, stream>>>(row1, part, N1, E1);
    hipMemcpyAsync(off1, row1, N1 * 4, hipMemcpyDeviceToDevice, stream);
    k_fill_edges<<<(E1 + 255) / 256, 256, 0, stream>>>(srcp1, ewp1, off1, src1, dst1, ew1, E1);
    k_deg_dinv<<<(N1 + 255) / 256, 256, 0, stream>>>(dinv1, row1, ewp1, N1);
    k_scale<<<(N1 + 255) / 256, 256, 0, stream>>>(ewp1, srcp1, row1, dinv1, N1);

    k_gemm<INCH><<<(N1 + 15) / 16, 256, 0, stream>>>(A1, x1, W1a, N1);
    k_conv<<<(N1 + 3) / 4, 256, 0, stream>>>(B1, A1, srcp1, ewp1, row1, dinv1, b1a, N1);
    k_gemm<HID><<<(N1 + 15) / 16, 256, 0, stream>>>(A1, B1, W1b, N1);
    k_conv<<<(N1 + 3) / 4, 256, 0, stream>>>(B1, A1, srcp1, ewp1, row1, dinv1, b1b, N1);

    hipMemsetAsync(segoff1, 0, NSEG * 4, stream);
    k_hist_seg<<<(N1 + 255) / 256, 256, 0, stream>>>(segoff1, ba1, nl, N1);
    k_scan1<<<(NSEG + 1023) / 1024, 256, 0, stream>>>(segoff1, segrow1, part, NSEG);
    k_scan2<<<1, 256, 0, stream>>>(part, (NSEG + 1023) / 1024);
    k_scan3<<<(NSEG + 255) / 256, 256, 0, stream>>>(segrow1, part, NSEG, N1);
    hipMemcpyAsync(segoff1, segrow1, NSEG * 4, hipMemcpyDeviceToDevice, stream);
    k_fill_seg<<<(N1 + 255) / 256, 256, 0, stream>>>(nodeid1, segoff1, ba1, nl, N1);
    k_pool<<<(NSEG + 3) / 4, 256, 0, stream>>>(emb1, esum, emb2, B1, nodeid1, segrow1);

    // ---------------- classifier ----------------
    k_cls<<<dim3(16, 16), 256, 0, stream>>>(hcls, esum, Wm1);
    k_bn<<<(BSZ * CLS + 255) / 256, 256, 0, stream>>>(hact, hcls, bm1, gam, bet, bmn, bvr);
    k_out<<<1, 256, 0, stream>>>(out, hact, Wm2, bm2);
}

// Round 4
// 1042.960 us; speedup vs baseline: 1.8338x; 1.2907x over previous
//
#include <hip/hip_runtime.h>
#include <hip/hip_bf16.h>

#define N1 131072
#define E1 2097152
#define N2 2368
#define E2 37888
#define NROIS 148
#define BSZ 16
#define HID 64
#define INCH 128
#define NSEG (BSZ*NROIS)      /* 2368 */
#define SDIM (NROIS*HID)      /* 9472 */
#define CLS 1000
#define OCH 2
#define KC 74                 /* 9472/128: split-K chunk for k_cls */

// ---------------- CSR build: histogram / scan / fill ----------------

__global__ void k_hist_dst(int* __restrict__ cnt, const int* __restrict__ dst, int E) {
    int e = blockIdx.x * 256 + threadIdx.x;
    if (e < E) atomicAdd(&cnt[dst[e]], 1);
}

__global__ void k_hist_seg(int* __restrict__ cnt, const int* __restrict__ batch,
                           const int* __restrict__ label, int n) {
    int i = blockIdx.x * 256 + threadIdx.x;
    if (i < n) atomicAdd(&cnt[batch[i] * NROIS + label[i]], 1);
}

// multi-block exclusive scan (for N1-sized arrays)
__global__ void k_scan1(const int* __restrict__ in, int* __restrict__ out,
                        int* __restrict__ part, int n) {
    __shared__ int sh[256];
    int t = threadIdx.x;
    int i0 = blockIdx.x * 1024 + t * 4;
    int v0 = (i0     < n) ? in[i0]     : 0;
    int v1 = (i0 + 1 < n) ? in[i0 + 1] : 0;
    int v2 = (i0 + 2 < n) ? in[i0 + 2] : 0;
    int v3 = (i0 + 3 < n) ? in[i0 + 3] : 0;
    int tot = v0 + v1 + v2 + v3;
    sh[t] = tot; __syncthreads();
    for (int off = 1; off < 256; off <<= 1) {
        int x = 0; if (t >= off) x = sh[t - off];
        __syncthreads();
        if (t >= off) sh[t] += x;
        __syncthreads();
    }
    int excl = sh[t] - tot;
    if (t == 255) part[blockIdx.x] = sh[255];
    if (i0     < n) out[i0]     = excl;
    if (i0 + 1 < n) out[i0 + 1] = excl + v0;
    if (i0 + 2 < n) out[i0 + 2] = excl + v0 + v1;
    if (i0 + 3 < n) out[i0 + 3] = excl + v0 + v1 + v2;
}

__global__ void k_scan2(int* __restrict__ part, int cnt) {
    __shared__ int sh[256];
    int t = threadIdx.x;
    int v = (t < cnt) ? part[t] : 0;
    sh[t] = v; __syncthreads();
    for (int off = 1; off < 256; off <<= 1) {
        int x = 0; if (t >= off) x = sh[t - off];
        __syncthreads();
        if (t >= off) sh[t] += x;
        __syncthreads();
    }
    if (t < cnt) part[t] = sh[t] - v;
}

__global__ void k_scan3(int* __restrict__ out, const int* __restrict__ part, int n, int total) {
    int i = blockIdx.x * 256 + threadIdx.x;
    if (i < n) out[i] += part[i >> 10];
    if (i == 0) out[n] = total;
}

// single-block exclusive scan for small arrays (n ~ few thousand); writes sentinel out[n]
__global__ void k_scan_one(const int* __restrict__ in, int* __restrict__ out, int n) {
    __shared__ int sh[256];
    __shared__ int carry;
    int t = threadIdx.x;
    if (t == 0) carry = 0;
    __syncthreads();
    for (int base = 0; base < n; base += 256) {
        int i = base + t;
        int v = (i < n) ? in[i] : 0;
        sh[t] = v; __syncthreads();
        for (int off = 1; off < 256; off <<= 1) {
            int x = 0; if (t >= off) x = sh[t - off];
            __syncthreads();
            if (t >= off) sh[t] += x;
            __syncthreads();
        }
        if (i < n) out[i] = carry + sh[t] - v;
        __syncthreads();
        if (t == 255) carry += sh[255];
        __syncthreads();
    }
    if (t == 0) out[n] = carry;
}

// fill CSR with (src, weight) 8-byte pairs
__global__ void k_fill_edges(int2* __restrict__ edges, int* __restrict__ off,
                             const int* __restrict__ src, const int* __restrict__ dst,
                             const float* __restrict__ ew, int E) {
    int e = blockIdx.x * 256 + threadIdx.x;
    if (e >= E) return;
    int pos = atomicAdd(&off[dst[e]], 1);
    edges[pos] = make_int2(src[e], __float_as_int(ew[e]));
}

__global__ void k_fill_seg(int* __restrict__ nodeid, int* __restrict__ off,
                           const int* __restrict__ batch, const int* __restrict__ label, int n) {
    int i = blockIdx.x * 256 + threadIdx.x;
    if (i >= n) return;
    int pos = atomicAdd(&off[batch[i] * NROIS + label[i]], 1);
    nodeid[pos] = i;
}

// dinv[d] = rsqrt(1 + sum of in-edge weights)
__global__ void k_deg_dinv(float* __restrict__ dinv, const int* __restrict__ row,
                           const int2* __restrict__ edges, int n) {
    int d = blockIdx.x * 256 + threadIdx.x;
    if (d >= n) return;
    int a = row[d], b = row[d + 1];
    float s = 1.0f;
    for (int i = a; i < b; i++) s += __int_as_float(edges[i].y);
    dinv[d] = rsqrtf(s);
}

// edge.w = dinv[src]*w*dinv[dst], in place
__global__ void k_scale(int2* __restrict__ edges, const int* __restrict__ row,
                        const float* __restrict__ dinv, int n) {
    int d = blockIdx.x * 256 + threadIdx.x;
    if (d >= n) return;
    int a = row[d], b = row[d + 1];
    float dd = dinv[d];
    for (int i = a; i < b; i++) {
        int2 e = edges[i];
        edges[i].y = __float_as_int(dinv[e.x] * __int_as_float(e.y) * dd);
    }
}

// ---------------- dense ops ----------------

// out[n][HID] = x[n][K] @ W[K][HID].  W in LDS, reused across 4 rows/thread.
// n must be a multiple of 16 (131072 and 2368 both are).
template <int K>
__global__ __launch_bounds__(256) void k_gemm(float* __restrict__ out,
                                              const float* __restrict__ x,
                                              const float* __restrict__ W, int n) {
    __shared__ float Wl[K * HID];
    int tid = threadIdx.x;
    {
        const float4* W4 = (const float4*)W;
        float4* Wl4 = (float4*)Wl;
        for (int i = tid; i < K * HID / 4; i += 256) Wl4[i] = W4[i];
    }
    __syncthreads();
    int col = tid & 63;
    int row = blockIdx.x * 16 + (tid >> 6) * 4;
    const float4* xr0 = (const float4*)(x + (size_t)(row + 0) * K);
    const float4* xr1 = (const float4*)(x + (size_t)(row + 1) * K);
    const float4* xr2 = (const float4*)(x + (size_t)(row + 2) * K);
    const float4* xr3 = (const float4*)(x + (size_t)(row + 3) * K);
    float a0 = 0.f, a1 = 0.f, a2 = 0.f, a3 = 0.f;
#pragma unroll 8
    for (int k4 = 0; k4 < K / 4; k4++) {
        float w0 = Wl[(k4 * 4 + 0) * HID + col];
        float w1 = Wl[(k4 * 4 + 1) * HID + col];
        float w2 = Wl[(k4 * 4 + 2) * HID + col];
        float w3 = Wl[(k4 * 4 + 3) * HID + col];
        float4 v0 = xr0[k4], v1 = xr1[k4], v2 = xr2[k4], v3 = xr3[k4];
        a0 += v0.x * w0 + v0.y * w1 + v0.z * w2 + v0.w * w3;
        a1 += v1.x * w0 + v1.y * w1 + v1.z * w2 + v1.w * w3;
        a2 += v2.x * w0 + v2.y * w1 + v2.z * w2 + v2.w * w3;
        a3 += v3.x * w0 + v3.y * w1 + v3.z * w2 + v3.w * w3;
    }
    out[(size_t)(row + 0) * HID + col] = a0;
    out[(size_t)(row + 1) * HID + col] = a1;
    out[(size_t)(row + 2) * HID + col] = a2;
    out[(size_t)(row + 3) * HID + col] = a3;
}

// fused GCN aggregate: wave per dst node, lane = feature column, 4-deep ILP.
__global__ __launch_bounds__(256) void k_conv(float* __restrict__ out, const float* __restrict__ h,
                                              const int2* __restrict__ edges,
                                              const int* __restrict__ row,
                                              const float* __restrict__ dinv,
                                              const float* __restrict__ bias, int n) {
    int d = blockIdx.x * 4 + (threadIdx.x >> 6);
    if (d >= n) return;
    int lane = threadIdx.x & 63;
    int a = row[d], b = row[d + 1];
    float ac0 = 0.f, ac1 = 0.f, ac2 = 0.f, ac3 = 0.f;
    for (int base = a; base < b; base += 64) {
        int m = b - base; if (m > 64) m = 64;
        int sv = 0, wv = 0;
        if (base + lane < b) { int2 e = edges[base + lane]; sv = e.x; wv = e.y; }
        int j = 0;
        for (; j + 3 < m; j += 4) {
            int s0 = __shfl(sv, j),     s1 = __shfl(sv, j + 1);
            int s2 = __shfl(sv, j + 2), s3 = __shfl(sv, j + 3);
            float w0 = __int_as_float(__shfl(wv, j));
            float w1 = __int_as_float(__shfl(wv, j + 1));
            float w2 = __int_as_float(__shfl(wv, j + 2));
            float w3 = __int_as_float(__shfl(wv, j + 3));
            float h0 = h[(size_t)s0 * HID + lane];
            float h1 = h[(size_t)s1 * HID + lane];
            float h2 = h[(size_t)s2 * HID + lane];
            float h3 = h[(size_t)s3 * HID + lane];
            ac0 += h0 * w0; ac1 += h1 * w1; ac2 += h2 * w2; ac3 += h3 * w3;
        }
        for (; j < m; j++) {
            int s0 = __shfl(sv, j);
            float w0 = __int_as_float(__shfl(wv, j));
            ac0 += h[(size_t)s0 * HID + lane] * w0;
        }
    }
    float di = dinv[d];
    float v = (ac0 + ac1) + (ac2 + ac3) + h[(size_t)d * HID + lane] * di * di + bias[lane];
    out[(size_t)d * HID + lane] = v > 0.f ? v : 0.f;
}

// segment-mean pool: wave per segment; counts from rowptr diff.
__global__ __launch_bounds__(256) void k_pool(float* __restrict__ emb, float* __restrict__ esum,
                                              const float* __restrict__ embo,
                                              const float* __restrict__ h,
                                              const int* __restrict__ nodeid,
                                              const int* __restrict__ segrow) {
    int s = blockIdx.x * 4 + (threadIdx.x >> 6);
    if (s >= NSEG) return;
    int lane = threadIdx.x & 63;
    int a = segrow[s], b = segrow[s + 1];
    float ac0 = 0.f, ac1 = 0.f, ac2 = 0.f, ac3 = 0.f;
    for (int base = a; base < b; base += 64) {
        int m = b - base; if (m > 64) m = 64;
        int nid = 0;
        if (base + lane < b) nid = nodeid[base + lane];
        int j = 0;
        for (; j + 3 < m; j += 4) {
            int n0 = __shfl(nid, j),     n1 = __shfl(nid, j + 1);
            int n2 = __shfl(nid, j + 2), n3 = __shfl(nid, j + 3);
            ac0 += h[(size_t)n0 * HID + lane];
            ac1 += h[(size_t)n1 * HID + lane];
            ac2 += h[(size_t)n2 * HID + lane];
            ac3 += h[(size_t)n3 * HID + lane];
        }
        for (; j < m; j++) {
            int n0 = __shfl(nid, j);
            ac0 += h[(size_t)n0 * HID + lane];
        }
    }
    float mean = ((ac0 + ac1) + (ac2 + ac3)) / fmaxf((float)(b - a), 1.0f);
    emb[(size_t)s * HID + lane] = mean;
    if (esum) esum[(size_t)s * HID + lane] = mean + embo[(size_t)s * HID + lane];
}

// ---------------- classifier ----------------

// hcls[16][1000] += s[16][9472] @ Wm1[9472][1000], split-K over 128 blocks.
// thread t covers cols [4t, 4t+4); 16 float4 accumulators (one per batch row).
__global__ __launch_bounds__(256) void k_cls(float* __restrict__ hcls,
                                             const float* __restrict__ s,
                                             const float* __restrict__ Wm1) {
    __shared__ float sl[KC * 16];
    int tid = threadIdx.x;
    int k0 = blockIdx.x * KC;
    for (int i = tid; i < KC * 16; i += 256) {
        int kk = i >> 4, b = i & 15;
        sl[i] = s[b * SDIM + k0 + kk];
    }
    __syncthreads();
    int c4 = tid * 4;
    bool active = c4 < CLS;
    const float zero4[4] = {0.f, 0.f, 0.f, 0.f};
    float4 acc[16];
#pragma unroll
    for (int b = 0; b < 16; b++) acc[b] = make_float4(0.f, 0.f, 0.f, 0.f);
    for (int kk = 0; kk < KC; kk++) {
        float4 w = active ? *(const float4*)(&Wm1[(size_t)(k0 + kk) * CLS + c4])
                          : *(const float4*)zero4;
#pragma unroll
        for (int b = 0; b < 16; b++) {
            float sv = sl[kk * 16 + b];
            acc[b].x += sv * w.x; acc[b].y += sv * w.y;
            acc[b].z += sv * w.z; acc[b].w += sv * w.w;
        }
    }
    if (active) {
#pragma unroll
        for (int b = 0; b < 16; b++) {
            unsafeAtomicAdd(&hcls[b * CLS + c4 + 0], acc[b].x);
            unsafeAtomicAdd(&hcls[b * CLS + c4 + 1], acc[b].y);
            unsafeAtomicAdd(&hcls[b * CLS + c4 + 2], acc[b].z);
            unsafeAtomicAdd(&hcls[b * CLS + c4 + 3], acc[b].w);
        }
    }
}

__global__ void k_bn(float* __restrict__ hact, const float* __restrict__ hcls,
                     const float* __restrict__ bm1, const float* __restrict__ gamma,
                     const float* __restrict__ beta, const float* __restrict__ mean,
                     const float* __restrict__ var) {
    int i = blockIdx.x * blockDim.x + threadIdx.x;
    if (i >= BSZ * CLS) return;
    int j = i % CLS;
    float t = hcls[i] + bm1[j];
    t = gamma[j] * (t - mean[j]) * rsqrtf(var[j] + 1e-5f) + beta[j];
    hact[i] = t > 0.f ? t : 0.01f * t;
}

__global__ void k_out(float* __restrict__ outp, const float* __restrict__ hact,
                      const float* __restrict__ Wm2, const float* __restrict__ bm2) {
    int tid = threadIdx.x;              // one block of 256
    int oi = tid >> 3, part = tid & 7;  // 32 outputs x 8 partials
    int b = oi >> 1, o = oi & 1;
    float acc = (part == 0) ? bm2[o] : 0.f;
    for (int k = part; k < CLS; k += 8) acc += hact[b * CLS + k] * Wm2[k * OCH + o];
    unsafeAtomicAdd(&outp[b * OCH + o], acc);
}

extern "C" void kernel_launch(void* const* d_in, const int* in_sizes, int n_in,
                              void* d_out, int out_size, void* d_ws, size_t ws_size,
                              hipStream_t stream) {
    const float* x1  = (const float*)d_in[0];
    const int*   nl  = (const int*)d_in[1];
    const int*   ei1 = (const int*)d_in[2];
    const float* ew1 = (const float*)d_in[3];
    const int*   ba1 = (const int*)d_in[4];
    const float* x2  = (const float*)d_in[5];
    const int*   rl  = (const int*)d_in[6];
    const int*   ei2 = (const int*)d_in[7];
    const float* ew2 = (const float*)d_in[8];
    const int*   ba2 = (const int*)d_in[9];
    const float* W1a = (const float*)d_in[10];
    const float* b1a = (const float*)d_in[11];
    const float* W1b = (const float*)d_in[12];
    const float* b1b = (const float*)d_in[13];
    const float* W2a = (const float*)d_in[14];
    const float* b2a = (const float*)d_in[15];
    const float* W2b = (const float*)d_in[16];
    const float* b2b = (const float*)d_in[17];
    const float* Wm1 = (const float*)d_in[18];
    const float* bm1 = (const float*)d_in[19];
    const float* gam = (const float*)d_in[20];
    const float* bet = (const float*)d_in[21];
    const float* bmn = (const float*)d_in[22];
    const float* bvr = (const float*)d_in[23];
    const float* Wm2 = (const float*)d_in[24];
    const float* bm2 = (const float*)d_in[25];

    float* out  = (float*)d_out;
    float* emb1 = out + 32;               // embedding        (16 x 9472)
    float* emb2 = emb1 + NSEG * HID;      // embedding_roi
    float* esum = emb2 + NSEG * HID;      // embedding + embedding_roi

    // ---- workspace carve ----
    char* p = (char*)d_ws;
    auto carve = [&](size_t nbytes) { char* q = p; p += (nbytes + 255) & ~(size_t)255; return (void*)q; };
    int*   row1    = (int*)  carve((N1 + 1) * 4);
    int*   off1    = (int*)  carve(N1 * 4);
    int2*  edges1  = (int2*) carve((size_t)E1 * 8);
    float* dinv1   = (float*)carve(N1 * 4);
    float* A1      = (float*)carve((size_t)N1 * HID * 4);
    float* B1      = (float*)carve((size_t)N1 * HID * 4);
    int*   nodeid1 = (int*)  carve(N1 * 4);
    int*   segrow1 = (int*)  carve((NSEG + 1) * 4);
    int*   segoff1 = (int*)  carve(NSEG * 4);
    int*   row2    = (int*)  carve((N2 + 1) * 4);
    int*   off2    = (int*)  carve(N2 * 4);
    int2*  edges2  = (int2*) carve((size_t)E2 * 8);
    float* dinv2   = (float*)carve(N2 * 4);
    float* A2      = (float*)carve((size_t)N2 * HID * 4);
    float* B2      = (float*)carve((size_t)N2 * HID * 4);
    int*   nodeid2 = (int*)  carve(N2 * 4);
    int*   segrow2 = (int*)  carve((NSEG + 1) * 4);
    int*   segoff2 = (int*)  carve(NSEG * 4);
    int*   part    = (int*)  carve(256 * 4);
    float* hcls    = (float*)carve(BSZ * CLS * 4);
    float* hact    = (float*)carve(BSZ * CLS * 4);

    const int* src1 = ei1;
    const int* dst1 = ei1 + E1;
    const int* src2 = ei2;
    const int* dst2 = ei2 + E2;

    hipMemsetAsync(d_out, 0, (size_t)out_size * sizeof(float), stream);
    hipMemsetAsync(hcls, 0, BSZ * CLS * sizeof(float), stream);

    // ---------------- graph 2 (ROI graph, small) ----------------
    hipMemsetAsync(off2, 0, N2 * 4, stream);
    k_hist_dst<<<(E2 + 255) / 256, 256, 0, stream>>>(off2, dst2, E2);
    k_scan_one<<<1, 256, 0, stream>>>(off2, row2, N2);
    hipMemcpyAsync(off2, row2, N2 * 4, hipMemcpyDeviceToDevice, stream);
    k_fill_edges<<<(E2 + 255) / 256, 256, 0, stream>>>(edges2, off2, src2, dst2, ew2, E2);
    k_deg_dinv<<<(N2 + 255) / 256, 256, 0, stream>>>(dinv2, row2, edges2, N2);
    k_scale<<<(N2 + 255) / 256, 256, 0, stream>>>(edges2, row2, dinv2, N2);

    k_gemm<INCH><<<N2 / 16, 256, 0, stream>>>(A2, x2, W2a, N2);
    k_conv<<<(N2 + 3) / 4, 256, 0, stream>>>(B2, A2, edges2, row2, dinv2, b2a, N2);
    k_gemm<HID><<<N2 / 16, 256, 0, stream>>>(A2, B2, W2b, N2);
    k_conv<<<(N2 + 3) / 4, 256, 0, stream>>>(B2, A2, edges2, row2, dinv2, b2b, N2);
    // graph-2 final features now in B2

    hipMemsetAsync(segoff2, 0, NSEG * 4, stream);
    k_hist_seg<<<(N2 + 255) / 256, 256, 0, stream>>>(segoff2, ba2, rl, N2);
    k_scan_one<<<1, 256, 0, stream>>>(segoff2, segrow2, NSEG);
    hipMemcpyAsync(segoff2, segrow2, NSEG * 4, hipMemcpyDeviceToDevice, stream);
    k_fill_seg<<<(N2 + 255) / 256, 256, 0, stream>>>(nodeid2, segoff2, ba2, rl, N2);
    k_pool<<<(NSEG + 3) / 4, 256, 0, stream>>>(emb2, (float*)nullptr, (const float*)nullptr,
                                               B2, nodeid2, segrow2);

    // ---------------- graph 1 (fine-grained, large) ----------------
    hipMemsetAsync(off1, 0, N1 * 4, stream);
    k_hist_dst<<<(E1 + 255) / 256, 256, 0, stream>>>(off1, dst1, E1);
    k_scan1<<<(N1 + 1023) / 1024, 256, 0, stream>>>(off1, row1, part, N1);
    k_scan2<<<1, 256, 0, stream>>>(part, (N1 + 1023) / 1024);
    k_scan3<<<(N1 + 255) / 256, 256, 0, stream>>>(row1, part, N1, E1);
    hipMemcpyAsync(off1, row1, N1 * 4, hipMemcpyDeviceToDevice, stream);
    k_fill_edges<<<(E1 + 255) / 256, 256, 0, stream>>>(edges1, off1, src1, dst1, ew1, E1);
    k_deg_dinv<<<(N1 + 255) / 256, 256, 0, stream>>>(dinv1, row1, edges1, N1);
    k_scale<<<(N1 + 255) / 256, 256, 0, stream>>>(edges1, row1, dinv1, N1);

    k_gemm<INCH><<<N1 / 16, 256, 0, stream>>>(A1, x1, W1a, N1);
    k_conv<<<(N1 + 3) / 4, 256, 0, stream>>>(B1, A1, edges1, row1, dinv1, b1a, N1);
    k_gemm<HID><<<N1 / 16, 256, 0, stream>>>(A1, B1, W1b, N1);
    k_conv<<<(N1 + 3) / 4, 256, 0, stream>>>(B1, A1, edges1, row1, dinv1, b1b, N1);

    hipMemsetAsync(segoff1, 0, NSEG * 4, stream);
    k_hist_seg<<<(N1 + 255) / 256, 256, 0, stream>>>(segoff1, ba1, nl, N1);
    k_scan_one<<<1, 256, 0, stream>>>(segoff1, segrow1, NSEG);
    hipMemcpyAsync(segoff1, segrow1, NSEG * 4, hipMemcpyDeviceToDevice, stream);
    k_fill_seg<<<(N1 + 255) / 256, 256, 0, stream>>>(nodeid1, segoff1, ba1, nl, N1);
    k_pool<<<(NSEG + 3) / 4, 256, 0, stream>>>(emb1, esum, emb2, B1, nodeid1, segrow1);

    // ---------------- classifier ----------------
    k_cls<<<SDIM / KC, 256, 0, stream>>>(hcls, esum, Wm1);
    k_bn<<<(BSZ * CLS + 255) / 256, 256, 0, stream>>>(hact, hcls, bm1, gam, bet, bmn, bvr);
    k_out<<<1, 256, 0, stream>>>(out, hact, Wm2, bm2);
}

// Round 5
// 918.123 us; speedup vs baseline: 2.0831x; 1.1360x over previous
//
#include <hip/hip_runtime.h>
#include <hip/hip_bf16.h>

#define N1 131072
#define E1 2097152
#define N2 2368
#define E2 37888
#define NROIS 148
#define BSZ 16
#define HID 64
#define INCH 128
#define NSEG (BSZ*NROIS)      /* 2368 */
#define SDIM (NROIS*HID)      /* 9472 */
#define CLS 1000
#define OCH 2
#define KC 74                 /* 9472/128: split-K chunk for k_cls */

// ---------------- CSR build: histogram / scan / fill ----------------

__global__ void k_hist_dst(int* __restrict__ cnt, const int* __restrict__ dst, int E) {
    int e = blockIdx.x * 256 + threadIdx.x;
    if (e < E) atomicAdd(&cnt[dst[e]], 1);
}

__global__ void k_hist_seg(int* __restrict__ cnt, const int* __restrict__ batch,
                           const int* __restrict__ label, int n) {
    int i = blockIdx.x * 256 + threadIdx.x;
    if (i < n) atomicAdd(&cnt[batch[i] * NROIS + label[i]], 1);
}

// multi-block exclusive scan (for N1-sized arrays)
__global__ void k_scan1(const int* __restrict__ in, int* __restrict__ out,
                        int* __restrict__ part, int n) {
    __shared__ int sh[256];
    int t = threadIdx.x;
    int i0 = blockIdx.x * 1024 + t * 4;
    int v0 = (i0     < n) ? in[i0]     : 0;
    int v1 = (i0 + 1 < n) ? in[i0 + 1] : 0;
    int v2 = (i0 + 2 < n) ? in[i0 + 2] : 0;
    int v3 = (i0 + 3 < n) ? in[i0 + 3] : 0;
    int tot = v0 + v1 + v2 + v3;
    sh[t] = tot; __syncthreads();
    for (int off = 1; off < 256; off <<= 1) {
        int x = 0; if (t >= off) x = sh[t - off];
        __syncthreads();
        if (t >= off) sh[t] += x;
        __syncthreads();
    }
    int excl = sh[t] - tot;
    if (t == 255) part[blockIdx.x] = sh[255];
    if (i0     < n) out[i0]     = excl;
    if (i0 + 1 < n) out[i0 + 1] = excl + v0;
    if (i0 + 2 < n) out[i0 + 2] = excl + v0 + v1;
    if (i0 + 3 < n) out[i0 + 3] = excl + v0 + v1 + v2;
}

__global__ void k_scan2(int* __restrict__ part, int cnt) {
    __shared__ int sh[256];
    int t = threadIdx.x;
    int v = (t < cnt) ? part[t] : 0;
    sh[t] = v; __syncthreads();
    for (int off = 1; off < 256; off <<= 1) {
        int x = 0; if (t >= off) x = sh[t - off];
        __syncthreads();
        if (t >= off) sh[t] += x;
        __syncthreads();
    }
    if (t < cnt) part[t] = sh[t] - v;
}

__global__ void k_scan3(int* __restrict__ out, const int* __restrict__ part, int n, int total) {
    int i = blockIdx.x * 256 + threadIdx.x;
    if (i < n) out[i] += part[i >> 10];
    if (i == 0) out[n] = total;
}

// single-block exclusive scan for small arrays; writes sentinel out[n]
__global__ void k_scan_one(const int* __restrict__ in, int* __restrict__ out, int n) {
    __shared__ int sh[256];
    __shared__ int carry;
    int t = threadIdx.x;
    if (t == 0) carry = 0;
    __syncthreads();
    for (int base = 0; base < n; base += 256) {
        int i = base + t;
        int v = (i < n) ? in[i] : 0;
        sh[t] = v; __syncthreads();
        for (int off = 1; off < 256; off <<= 1) {
            int x = 0; if (t >= off) x = sh[t - off];
            __syncthreads();
            if (t >= off) sh[t] += x;
            __syncthreads();
        }
        if (i < n) out[i] = carry + sh[t] - v;
        __syncthreads();
        if (t == 255) carry += sh[255];
        __syncthreads();
    }
    if (t == 0) out[n] = carry;
}

// fill CSR with (src, weight) 8-byte pairs
__global__ void k_fill_edges(int2* __restrict__ edges, int* __restrict__ off,
                             const int* __restrict__ src, const int* __restrict__ dst,
                             const float* __restrict__ ew, int E) {
    int e = blockIdx.x * 256 + threadIdx.x;
    if (e >= E) return;
    int pos = atomicAdd(&off[dst[e]], 1);
    edges[pos] = make_int2(src[e], __float_as_int(ew[e]));
}

__global__ void k_fill_seg(int* __restrict__ nodeid, int* __restrict__ off,
                           const int* __restrict__ batch, const int* __restrict__ label, int n) {
    int i = blockIdx.x * 256 + threadIdx.x;
    if (i >= n) return;
    int pos = atomicAdd(&off[batch[i] * NROIS + label[i]], 1);
    nodeid[pos] = i;
}

// dinv[d] = rsqrt(1 + sum of in-edge weights)
__global__ void k_deg_dinv(float* __restrict__ dinv, const int* __restrict__ row,
                           const int2* __restrict__ edges, int n) {
    int d = blockIdx.x * 256 + threadIdx.x;
    if (d >= n) return;
    int a = row[d], b = row[d + 1];
    float s = 1.0f;
    for (int i = a; i < b; i++) s += __int_as_float(edges[i].y);
    dinv[d] = rsqrtf(s);
}

// edge.w = dinv[src]*w*dinv[dst], in place
__global__ void k_scale(int2* __restrict__ edges, const int* __restrict__ row,
                        const float* __restrict__ dinv, int n) {
    int d = blockIdx.x * 256 + threadIdx.x;
    if (d >= n) return;
    int a = row[d], b = row[d + 1];
    float dd = dinv[d];
    for (int i = a; i < b; i++) {
        int2 e = edges[i];
        edges[i].y = __float_as_int(dinv[e.x] * __int_as_float(e.y) * dd);
    }
}

// ---------------- dense ops ----------------

// out[n][64] = x[n][K] @ W[K][64].
// Block: 256 rows x 64 cols; thread tile 8x8 (32 rowgroups x 8 colgroups).
// K staged in 32-chunks: W chunk (8 KB) + x chunk (256x32, stride 37 pad) in LDS.
template <int K>
__global__ __launch_bounds__(256) void k_gemm(float* __restrict__ out,
                                              const float* __restrict__ x,
                                              const float* __restrict__ W, int n) {
    __shared__ float Wl[32 * 64];       // [kk][col]
    __shared__ float xs[256 * 37];      // [r][kk], stride 37 (bank-spread, b32 reads)
    int tid = threadIdx.x;
    int row0 = blockIdx.x * 256;
    int r0 = (tid >> 3) * 8;
    int c0 = (tid & 7) * 8;
    float acc[8][8];
#pragma unroll
    for (int i = 0; i < 8; i++)
#pragma unroll
        for (int j = 0; j < 8; j++) acc[i][j] = 0.f;

    for (int k0 = 0; k0 < K; k0 += 32) {
        __syncthreads();
        {   // stage W rows k0..k0+31 (contiguous 2048 floats)
            const float4* W4 = (const float4*)(W + k0 * 64);
            float4* Wl4 = (float4*)Wl;
#pragma unroll
            for (int i = 0; i < 2; i++) Wl4[tid + i * 256] = W4[tid + i * 256];
        }
        // stage x[row0..row0+256)[k0..k0+32)
#pragma unroll
        for (int i = 0; i < 8; i++) {
            int idx = tid + i * 256;
            int r = idx >> 3, kq = idx & 7;
            float4 v = make_float4(0.f, 0.f, 0.f, 0.f);
            if (row0 + r < n)
                v = *(const float4*)(x + (size_t)(row0 + r) * K + k0 + kq * 4);
            xs[r * 37 + kq * 4 + 0] = v.x;
            xs[r * 37 + kq * 4 + 1] = v.y;
            xs[r * 37 + kq * 4 + 2] = v.z;
            xs[r * 37 + kq * 4 + 3] = v.w;
        }
        __syncthreads();
#pragma unroll 2
        for (int kk = 0; kk < 32; kk++) {
            float4 wlo = *(const float4*)(&Wl[kk * 64 + c0]);
            float4 whi = *(const float4*)(&Wl[kk * 64 + c0 + 4]);
            float xf[8];
#pragma unroll
            for (int i = 0; i < 8; i++) xf[i] = xs[(r0 + i) * 37 + kk];
#pragma unroll
            for (int i = 0; i < 8; i++) {
                acc[i][0] += xf[i] * wlo.x; acc[i][1] += xf[i] * wlo.y;
                acc[i][2] += xf[i] * wlo.z; acc[i][3] += xf[i] * wlo.w;
                acc[i][4] += xf[i] * whi.x; acc[i][5] += xf[i] * whi.y;
                acc[i][6] += xf[i] * whi.z; acc[i][7] += xf[i] * whi.w;
            }
        }
    }
#pragma unroll
    for (int i = 0; i < 8; i++) {
        int row = row0 + r0 + i;
        if (row < n) {
            *(float4*)(&out[(size_t)row * 64 + c0]) =
                make_float4(acc[i][0], acc[i][1], acc[i][2], acc[i][3]);
            *(float4*)(&out[(size_t)row * 64 + c0 + 4]) =
                make_float4(acc[i][4], acc[i][5], acc[i][6], acc[i][7]);
        }
    }
}

// fused GCN aggregate: wave per dst node, lane = feature column, 8-deep ILP.
__global__ __launch_bounds__(256) void k_conv(float* __restrict__ out, const float* __restrict__ h,
                                              const int2* __restrict__ edges,
                                              const int* __restrict__ row,
                                              const float* __restrict__ dinv,
                                              const float* __restrict__ bias, int n) {
    int d = blockIdx.x * 4 + (threadIdx.x >> 6);
    if (d >= n) return;
    int lane = threadIdx.x & 63;
    int a = row[d], b = row[d + 1];
    float acc[8] = {0.f, 0.f, 0.f, 0.f, 0.f, 0.f, 0.f, 0.f};
    for (int base = a; base < b; base += 64) {
        int m = b - base; if (m > 64) m = 64;
        int sv = 0, wv = 0;
        if (base + lane < b) { int2 e = edges[base + lane]; sv = e.x; wv = e.y; }
        int j = 0;
        for (; j + 7 < m; j += 8) {
#pragma unroll
            for (int q = 0; q < 8; q++) {
                int s = __shfl(sv, j + q);
                float w = __int_as_float(__shfl(wv, j + q));
                acc[q] += h[(size_t)s * HID + lane] * w;
            }
        }
        for (; j < m; j++) {
            int s = __shfl(sv, j);
            float w = __int_as_float(__shfl(wv, j));
            acc[0] += h[(size_t)s * HID + lane] * w;
        }
    }
    float di = dinv[d];
    float v = ((acc[0] + acc[1]) + (acc[2] + acc[3])) + ((acc[4] + acc[5]) + (acc[6] + acc[7]))
              + h[(size_t)d * HID + lane] * di * di + bias[lane];
    out[(size_t)d * HID + lane] = v > 0.f ? v : 0.f;
}

// segment-mean pool: wave per segment; counts from rowptr diff.
__global__ __launch_bounds__(256) void k_pool(float* __restrict__ emb, float* __restrict__ esum,
                                              const float* __restrict__ embo,
                                              const float* __restrict__ h,
                                              const int* __restrict__ nodeid,
                                              const int* __restrict__ segrow) {
    int s = blockIdx.x * 4 + (threadIdx.x >> 6);
    if (s >= NSEG) return;
    int lane = threadIdx.x & 63;
    int a = segrow[s], b = segrow[s + 1];
    float ac0 = 0.f, ac1 = 0.f, ac2 = 0.f, ac3 = 0.f;
    for (int base = a; base < b; base += 64) {
        int m = b - base; if (m > 64) m = 64;
        int nid = 0;
        if (base + lane < b) nid = nodeid[base + lane];
        int j = 0;
        for (; j + 3 < m; j += 4) {
            int n0 = __shfl(nid, j),     n1 = __shfl(nid, j + 1);
            int n2 = __shfl(nid, j + 2), n3 = __shfl(nid, j + 3);
            ac0 += h[(size_t)n0 * HID + lane];
            ac1 += h[(size_t)n1 * HID + lane];
            ac2 += h[(size_t)n2 * HID + lane];
            ac3 += h[(size_t)n3 * HID + lane];
        }
        for (; j < m; j++) {
            int n0 = __shfl(nid, j);
            ac0 += h[(size_t)n0 * HID + lane];
        }
    }
    float mean = ((ac0 + ac1) + (ac2 + ac3)) / fmaxf((float)(b - a), 1.0f);
    emb[(size_t)s * HID + lane] = mean;
    if (esum) esum[(size_t)s * HID + lane] = mean + embo[(size_t)s * HID + lane];
}

// ---------------- classifier ----------------

// hcls[16][1000] += s[16][9472] @ Wm1[9472][1000], split-K over 128 blocks.
__global__ __launch_bounds__(256) void k_cls(float* __restrict__ hcls,
                                             const float* __restrict__ s,
                                             const float* __restrict__ Wm1) {
    __shared__ float sl[KC * 16];
    int tid = threadIdx.x;
    int k0 = blockIdx.x * KC;
    for (int i = tid; i < KC * 16; i += 256) {
        int kk = i >> 4, b = i & 15;
        sl[i] = s[b * SDIM + k0 + kk];
    }
    __syncthreads();
    int c4 = tid * 4;
    bool active = c4 < CLS;
    const float zero4[4] = {0.f, 0.f, 0.f, 0.f};
    float4 acc[16];
#pragma unroll
    for (int b = 0; b < 16; b++) acc[b] = make_float4(0.f, 0.f, 0.f, 0.f);
    for (int kk = 0; kk < KC; kk++) {
        float4 w = active ? *(const float4*)(&Wm1[(size_t)(k0 + kk) * CLS + c4])
                          : *(const float4*)zero4;
#pragma unroll
        for (int b = 0; b < 16; b++) {
            float sv = sl[kk * 16 + b];
            acc[b].x += sv * w.x; acc[b].y += sv * w.y;
            acc[b].z += sv * w.z; acc[b].w += sv * w.w;
        }
    }
    if (active) {
#pragma unroll
        for (int b = 0; b < 16; b++) {
            unsafeAtomicAdd(&hcls[b * CLS + c4 + 0], acc[b].x);
            unsafeAtomicAdd(&hcls[b * CLS + c4 + 1], acc[b].y);
            unsafeAtomicAdd(&hcls[b * CLS + c4 + 2], acc[b].z);
            unsafeAtomicAdd(&hcls[b * CLS + c4 + 3], acc[b].w);
        }
    }
}

__global__ void k_bn(float* __restrict__ hact, const float* __restrict__ hcls,
                     const float* __restrict__ bm1, const float* __restrict__ gamma,
                     const float* __restrict__ beta, const float* __restrict__ mean,
                     const float* __restrict__ var) {
    int i = blockIdx.x * blockDim.x + threadIdx.x;
    if (i >= BSZ * CLS) return;
    int j = i % CLS;
    float t = hcls[i] + bm1[j];
    t = gamma[j] * (t - mean[j]) * rsqrtf(var[j] + 1e-5f) + beta[j];
    hact[i] = t > 0.f ? t : 0.01f * t;
}

__global__ void k_out(float* __restrict__ outp, const float* __restrict__ hact,
                      const float* __restrict__ Wm2, const float* __restrict__ bm2) {
    int tid = threadIdx.x;              // one block of 256
    int oi = tid >> 3, part = tid & 7;  // 32 outputs x 8 partials
    int b = oi >> 1, o = oi & 1;
    float acc = (part == 0) ? bm2[o] : 0.f;
    for (int k = part; k < CLS; k += 8) acc += hact[b * CLS + k] * Wm2[k * OCH + o];
    unsafeAtomicAdd(&outp[b * OCH + o], acc);
}

extern "C" void kernel_launch(void* const* d_in, const int* in_sizes, int n_in,
                              void* d_out, int out_size, void* d_ws, size_t ws_size,
                              hipStream_t stream) {
    const float* x1  = (const float*)d_in[0];
    const int*   nl  = (const int*)d_in[1];
    const int*   ei1 = (const int*)d_in[2];
    const float* ew1 = (const float*)d_in[3];
    const int*   ba1 = (const int*)d_in[4];
    const float* x2  = (const float*)d_in[5];
    const int*   rl  = (const int*)d_in[6];
    const int*   ei2 = (const int*)d_in[7];
    const float* ew2 = (const float*)d_in[8];
    const int*   ba2 = (const int*)d_in[9];
    const float* W1a = (const float*)d_in[10];
    const float* b1a = (const float*)d_in[11];
    const float* W1b = (const float*)d_in[12];
    const float* b1b = (const float*)d_in[13];
    const float* W2a = (const float*)d_in[14];
    const float* b2a = (const float*)d_in[15];
    const float* W2b = (const float*)d_in[16];
    const float* b2b = (const float*)d_in[17];
    const float* Wm1 = (const float*)d_in[18];
    const float* bm1 = (const float*)d_in[19];
    const float* gam = (const float*)d_in[20];
    const float* bet = (const float*)d_in[21];
    const float* bmn = (const float*)d_in[22];
    const float* bvr = (const float*)d_in[23];
    const float* Wm2 = (const float*)d_in[24];
    const float* bm2 = (const float*)d_in[25];

    float* out  = (float*)d_out;
    float* emb1 = out + 32;               // embedding        (16 x 9472)
    float* emb2 = emb1 + NSEG * HID;      // embedding_roi
    float* esum = emb2 + NSEG * HID;      // embedding + embedding_roi

    // ---- workspace carve ----
    char* p = (char*)d_ws;
    auto carve = [&](size_t nbytes) { char* q = p; p += (nbytes + 255) & ~(size_t)255; return (void*)q; };
    int*   row1    = (int*)  carve((N1 + 1) * 4);
    int*   off1    = (int*)  carve(N1 * 4);
    int2*  edges1  = (int2*) carve((size_t)E1 * 8);
    float* dinv1   = (float*)carve(N1 * 4);
    float* A1      = (float*)carve((size_t)N1 * HID * 4);
    float* B1      = (float*)carve((size_t)N1 * HID * 4);
    int*   nodeid1 = (int*)  carve(N1 * 4);
    int*   segrow1 = (int*)  carve((NSEG + 1) * 4);
    int*   segoff1 = (int*)  carve(NSEG * 4);
    int*   row2    = (int*)  carve((N2 + 1) * 4);
    int*   off2    = (int*)  carve(N2 * 4);
    int2*  edges2  = (int2*) carve((size_t)E2 * 8);
    float* dinv2   = (float*)carve(N2 * 4);
    float* A2      = (float*)carve((size_t)N2 * HID * 4);
    float* B2      = (float*)carve((size_t)N2 * HID * 4);
    int*   nodeid2 = (int*)  carve(N2 * 4);
    int*   segrow2 = (int*)  carve((NSEG + 1) * 4);
    int*   segoff2 = (int*)  carve(NSEG * 4);
    int*   part    = (int*)  carve(256 * 4);
    float* hcls    = (float*)carve(BSZ * CLS * 4);
    float* hact    = (float*)carve(BSZ * CLS * 4);

    const int* src1 = ei1;
    const int* dst1 = ei1 + E1;
    const int* src2 = ei2;
    const int* dst2 = ei2 + E2;

    hipMemsetAsync(d_out, 0, (size_t)out_size * sizeof(float), stream);
    hipMemsetAsync(hcls, 0, BSZ * CLS * sizeof(float), stream);

    // ---------------- graph 2 (ROI graph, small) ----------------
    hipMemsetAsync(off2, 0, N2 * 4, stream);
    k_hist_dst<<<(E2 + 255) / 256, 256, 0, stream>>>(off2, dst2, E2);
    k_scan_one<<<1, 256, 0, stream>>>(off2, row2, N2);
    hipMemcpyAsync(off2, row2, N2 * 4, hipMemcpyDeviceToDevice, stream);
    k_fill_edges<<<(E2 + 255) / 256, 256, 0, stream>>>(edges2, off2, src2, dst2, ew2, E2);
    k_deg_dinv<<<(N2 + 255) / 256, 256, 0, stream>>>(dinv2, row2, edges2, N2);
    k_scale<<<(N2 + 255) / 256, 256, 0, stream>>>(edges2, row2, dinv2, N2);

    k_gemm<INCH><<<(N2 + 255) / 256, 256, 0, stream>>>(A2, x2, W2a, N2);
    k_conv<<<(N2 + 3) / 4, 256, 0, stream>>>(B2, A2, edges2, row2, dinv2, b2a, N2);
    k_gemm<HID><<<(N2 + 255) / 256, 256, 0, stream>>>(A2, B2, W2b, N2);
    k_conv<<<(N2 + 3) / 4, 256, 0, stream>>>(B2, A2, edges2, row2, dinv2, b2b, N2);
    // graph-2 final features now in B2

    hipMemsetAsync(segoff2, 0, NSEG * 4, stream);
    k_hist_seg<<<(N2 + 255) / 256, 256, 0, stream>>>(segoff2, ba2, rl, N2);
    k_scan_one<<<1, 256, 0, stream>>>(segoff2, segrow2, NSEG);
    hipMemcpyAsync(segoff2, segrow2, NSEG * 4, hipMemcpyDeviceToDevice, stream);
    k_fill_seg<<<(N2 + 255) / 256, 256, 0, stream>>>(nodeid2, segoff2, ba2, rl, N2);
    k_pool<<<(NSEG + 3) / 4, 256, 0, stream>>>(emb2, (float*)nullptr, (const float*)nullptr,
                                               B2, nodeid2, segrow2);

    // ---------------- graph 1 (fine-grained, large) ----------------
    hipMemsetAsync(off1, 0, N1 * 4, stream);
    k_hist_dst<<<(E1 + 255) / 256, 256, 0, stream>>>(off1, dst1, E1);
    k_scan1<<<(N1 + 1023) / 1024, 256, 0, stream>>>(off1, row1, part, N1);
    k_scan2<<<1, 256, 0, stream>>>(part, (N1 + 1023) / 1024);
    k_scan3<<<(N1 + 255) / 256, 256, 0, stream>>>(row1, part, N1, E1);
    hipMemcpyAsync(off1, row1, N1 * 4, hipMemcpyDeviceToDevice, stream);
    k_fill_edges<<<(E1 + 255) / 256, 256, 0, stream>>>(edges1, off1, src1, dst1, ew1, E1);
    k_deg_dinv<<<(N1 + 255) / 256, 256, 0, stream>>>(dinv1, row1, edges1, N1);
    k_scale<<<(N1 + 255) / 256, 256, 0, stream>>>(edges1, row1, dinv1, N1);

    k_gemm<INCH><<<N1 / 256, 256, 0, stream>>>(A1, x1, W1a, N1);
    k_conv<<<(N1 + 3) / 4, 256, 0, stream>>>(B1, A1, edges1, row1, dinv1, b1a, N1);
    k_gemm<HID><<<N1 / 256, 256, 0, stream>>>(A1, B1, W1b, N1);
    k_conv<<<(N1 + 3) / 4, 256, 0, stream>>>(B1, A1, edges1, row1, dinv1, b1b, N1);

    hipMemsetAsync(segoff1, 0, NSEG * 4, stream);
    k_hist_seg<<<(N1 + 255) / 256, 256, 0, stream>>>(segoff1, ba1, nl, N1);
    k_scan_one<<<1, 256, 0, stream>>>(segoff1, segrow1, NSEG);
    hipMemcpyAsync(segoff1, segrow1, NSEG * 4, hipMemcpyDeviceToDevice, stream);
    k_fill_seg<<<(N1 + 255) / 256, 256, 0, stream>>>(nodeid1, segoff1, ba1, nl, N1);
    k_pool<<<(NSEG + 3) / 4, 256, 0, stream>>>(emb1, esum, emb2, B1, nodeid1, segrow1);

    // ---------------- classifier ----------------
    k_cls<<<SDIM / KC, 256, 0, stream>>>(hcls, esum, Wm1);
    k_bn<<<(BSZ * CLS + 255) / 256, 256, 0, stream>>>(hact, hcls, bm1, gam, bet, bmn, bvr);
    k_out<<<1, 256, 0, stream>>>(out, hact, Wm2, bm2);
}